// Round 2
// baseline (1247.418 us; speedup 1.0000x reference)
//
#include <hip/hip_runtime.h>
#include <hip/hip_bf16.h>

// Shapes: B=32, L=256, D=1024, ALIGN=1024, FF=2048, NC=3
// Precision strategy: bf16x3 split emulation (~fp32 accuracy) for ALL GEMMs.
// Each fp32 x is stored as (hi, lo) bf16 planes: hi = RNE(x), lo = RNE(x - hi)
// (x - hi exact by Sterbenz). GEMM computes Ah*Bh + Ah*Bl + Al*Bh on the fp32
// MFMA accumulator; omitted lo*lo term is ~2^-18 relative -- negligible.

typedef __attribute__((ext_vector_type(8))) short short8_t;   // 8 bf16
typedef __attribute__((ext_vector_type(4))) float float4_t;   // 4 fp32

#define DEVI static __device__ __forceinline__

DEVI short f2bf(float f) {
  union { float f; unsigned u; } v; v.f = f;
  unsigned r = v.u + 0x7fffu + ((v.u >> 16) & 1u);   // RNE
  return (short)(r >> 16);
}
DEVI float bf2f(short s) {
  union { unsigned u; float f; } v;
  v.u = ((unsigned)(unsigned short)s) << 16;
  return v.f;
}
DEVI void split2(float x, short& hi, short& lo) {
  hi = f2bf(x);
  lo = f2bf(x - bf2f(hi));
}
DEVI float fast_tanh(float x) {
  float e = __expf(2.0f * x);
  return 1.0f - 2.0f / (e + 1.0f);
}

// ---------------------------------------------------------------------------
// Split-bf16 NT GEMM: C = op(A) * op(B)^T with A = Ah+Al, B = Bh+Bl.
// 128x128 tile, BK=32, 256 threads (4 waves, 2x2 of 64x64), each wave 4x4 of
// 16x16x32 MFMAs, 3 MFMAs per product (hh, hl, lh).
// OUT_MODE: 0 = fp32 store (Ch as float*), 1 = split bf16 store (Ch,Cl),
//           2 = tanh+column-sum -> agg (V GEMM: 16384 rows = [Cat1;Cat2]).
// N % 128 == 0, K % 32 == 0; A/B must be readable for full 128-row tiles
// (pad allocations when M < gridX*128); stores guarded by gm < M.
// ---------------------------------------------------------------------------
template <int DO_TANH, int OUT_MODE>
__global__ __launch_bounds__(256) void gemm_nt_split(
    const short* __restrict__ Ah, const short* __restrict__ Al, int lda, long sA,
    const short* __restrict__ Bh, const short* __restrict__ Bl, int ldb, long sB,
    void* __restrict__ Ch, void* __restrict__ Cl, int ldc, long sC,
    const float* __restrict__ bias,
    int M, int K,
    float* __restrict__ agg)
{
  __shared__ __align__(16) short Ash[128][40];
  __shared__ __align__(16) short Asl[128][40];
  __shared__ __align__(16) short Bsh[128][40];
  __shared__ __align__(16) short Bsl[128][40];

  const int z = blockIdx.z;
  Ah += (size_t)z * sA;  Al += (size_t)z * sA;
  Bh += (size_t)z * sB;  Bl += (size_t)z * sB;

  const int row0 = blockIdx.x * 128;
  const int col0 = blockIdx.y * 128;

  const int t    = threadIdx.x;
  const int lane = t & 63;
  const int wave = t >> 6;
  const int wr = wave >> 1, wc = wave & 1;
  const int m15 = lane & 15, q = lane >> 4;

  float4_t acc[4][4];
#pragma unroll
  for (int i = 0; i < 4; ++i)
#pragma unroll
    for (int j = 0; j < 4; ++j) acc[i][j] = (float4_t)0.0f;

  for (int k0 = 0; k0 < K; k0 += 32) {
#pragma unroll
    for (int i = 0; i < 2; ++i) {
      int c  = t + 256 * i;       // 0..511
      int r  = c >> 2;            // 0..127
      int kc = (c & 3) << 3;      // 0,8,16,24
      size_t ao = (size_t)(row0 + r) * lda + k0 + kc;
      size_t bo = (size_t)(col0 + r) * ldb + k0 + kc;
      *(int4*)(&Ash[r][kc]) = *(const int4*)(Ah + ao);
      *(int4*)(&Asl[r][kc]) = *(const int4*)(Al + ao);
      *(int4*)(&Bsh[r][kc]) = *(const int4*)(Bh + bo);
      *(int4*)(&Bsl[r][kc]) = *(const int4*)(Bl + bo);
    }
    __syncthreads();

    short8_t ah[4], al[4];
#pragma unroll
    for (int i = 0; i < 4; ++i) {
      ah[i] = *(const short8_t*)(&Ash[wr * 64 + i * 16 + m15][q * 8]);
      al[i] = *(const short8_t*)(&Asl[wr * 64 + i * 16 + m15][q * 8]);
    }
#pragma unroll
    for (int j = 0; j < 4; ++j) {
      short8_t bh = *(const short8_t*)(&Bsh[wc * 64 + j * 16 + m15][q * 8]);
      short8_t bl = *(const short8_t*)(&Bsl[wc * 64 + j * 16 + m15][q * 8]);
#pragma unroll
      for (int i = 0; i < 4; ++i) {
        acc[i][j] = __builtin_amdgcn_mfma_f32_16x16x32_bf16(ah[i], bh, acc[i][j], 0, 0, 0);
        acc[i][j] = __builtin_amdgcn_mfma_f32_16x16x32_bf16(ah[i], bl, acc[i][j], 0, 0, 0);
        acc[i][j] = __builtin_amdgcn_mfma_f32_16x16x32_bf16(al[i], bh, acc[i][j], 0, 0, 0);
      }
    }
    __syncthreads();
  }

  if (OUT_MODE == 2) {
    // tanh + column sum into agg[b][half*2048 + col]
    const int half = row0 >= 8192;
    const int b    = (row0 & 8191) >> 8;
#pragma unroll
    for (int j = 0; j < 4; ++j) {
      float s = 0.0f;
#pragma unroll
      for (int i = 0; i < 4; ++i)
#pragma unroll
        for (int r = 0; r < 4; ++r) s += fast_tanh(acc[i][j][r]);
      s += __shfl_xor(s, 16);
      s += __shfl_xor(s, 32);
      if (q == 0) {
        int col = col0 + wc * 64 + j * 16 + m15;
        atomicAdd(&agg[(size_t)b * 4096 + half * 2048 + col], s);
      }
    }
  } else {
    short* Chs = (short*)Ch + (size_t)z * sC;
    short* Cls = (short*)Cl + (size_t)z * sC;
    float* Cf  = (float*)Ch + (size_t)z * sC;
#pragma unroll
    for (int i = 0; i < 4; ++i) {
#pragma unroll
      for (int r = 0; r < 4; ++r) {
        int gm = row0 + wr * 64 + i * 16 + q * 4 + r;
        if (gm < M) {
#pragma unroll
          for (int j = 0; j < 4; ++j) {
            int gn = col0 + wc * 64 + j * 16 + m15;
            float v = acc[i][j][r];
            if (bias) v += bias[gn];
            if (DO_TANH) v = fast_tanh(v);
            if (OUT_MODE == 1) {
              short hi, lo; split2(v, hi, lo);
              Chs[(size_t)gm * ldc + gn] = hi;
              Cls[(size_t)gm * ldc + gn] = lo;
            } else {
              Cf[(size_t)gm * ldc + gn] = v;
            }
          }
        }
      }
    }
  }
}

// --- fp32 -> split bf16 transpose (batched): out[z][c][r] = in[z][r][c] ---
__global__ __launch_bounds__(256) void transpose_split(
    const float* __restrict__ in, short* __restrict__ oh, short* __restrict__ ol,
    int R, int C, long sIn, long sOut)
{
  __shared__ float tile[32][33];
  in += (size_t)blockIdx.z * sIn;
  oh += (size_t)blockIdx.z * sOut;
  ol += (size_t)blockIdx.z * sOut;
  const int tx = threadIdx.x & 31, ty = threadIdx.x >> 5;
  const int c0 = blockIdx.x * 32, r0 = blockIdx.y * 32;
#pragma unroll
  for (int i = 0; i < 4; ++i) {
    int r = ty + i * 8;
    tile[r][tx] = in[(size_t)(r0 + r) * C + c0 + tx];
  }
  __syncthreads();
#pragma unroll
  for (int i = 0; i < 4; ++i) {
    int cc = ty + i * 8;
    float v = tile[tx][cc];
    short hi, lo; split2(v, hi, lo);
    size_t o = (size_t)(c0 + cc) * R + r0 + tx;
    oh[o] = hi;
    ol[o] = lo;
  }
}

// --- bf16 -> bf16 transpose (batched), used for attn planes ---
__global__ __launch_bounds__(256) void transpose_b2b(
    const short* __restrict__ in, short* __restrict__ out,
    int R, int C, long sIn, long sOut)
{
  __shared__ short tile[32][33];
  in  += (size_t)blockIdx.z * sIn;
  out += (size_t)blockIdx.z * sOut;
  const int tx = threadIdx.x & 31, ty = threadIdx.x >> 5;
  const int c0 = blockIdx.x * 32, r0 = blockIdx.y * 32;
#pragma unroll
  for (int i = 0; i < 4; ++i) {
    int r = ty + i * 8;
    tile[r][tx] = in[(size_t)(r0 + r) * C + c0 + tx];
  }
  __syncthreads();
#pragma unroll
  for (int i = 0; i < 4; ++i) {
    int cc = ty + i * 8;
    out[(size_t)(c0 + cc) * R + r0 + tx] = tile[tx][cc];
  }
}

// --- fp32 -> split bf16, row_len input cols -> out_stride-strided rows ---
__global__ __launch_bounds__(256) void conv_split(
    const float* __restrict__ in, short* __restrict__ oh, short* __restrict__ ol,
    int row_len, int out_stride)
{
  size_t i = ((size_t)blockIdx.x * 256 + threadIdx.x) * 4;
  float4 v = *(const float4*)&in[i];
  size_t row = i / (unsigned)row_len;
  int col    = (int)(i - row * row_len);
  size_t o = row * out_stride + col;
  short4 h, l;
  split2(v.x, h.x, l.x); split2(v.y, h.y, l.y);
  split2(v.z, h.z, l.z); split2(v.w, h.w, l.w);
  *(short4*)&oh[o] = h;
  *(short4*)&ol[o] = l;
}

__global__ __launch_bounds__(256) void zero_f32(float* __restrict__ p, int n)
{
  int i = blockIdx.x * 256 + threadIdx.x;
  if (i < n) p[i] = 0.0f;
}

// --- softmax over rows of 256 (one wave per row), fp32 in -> split bf16 ---
__global__ __launch_bounds__(256) void softmax_rows(
    const float* __restrict__ e, short* __restrict__ oh, short* __restrict__ ol)
{
  const int row  = blockIdx.x * 4 + (threadIdx.x >> 6);
  const int lane = threadIdx.x & 63;
  const float4 v = *(const float4*)&e[(size_t)row * 256 + lane * 4];
  float m = fmaxf(fmaxf(v.x, v.y), fmaxf(v.z, v.w));
#pragma unroll
  for (int off = 32; off; off >>= 1) m = fmaxf(m, __shfl_xor(m, off));
  float e0 = __expf(v.x - m), e1 = __expf(v.y - m);
  float e2 = __expf(v.z - m), e3 = __expf(v.w - m);
  float s = e0 + e1 + e2 + e3;
#pragma unroll
  for (int off = 32; off; off >>= 1) s += __shfl_xor(s, off);
  float inv = 1.0f / s;
  short4 h, l;
  split2(e0 * inv, h.x, l.x); split2(e1 * inv, h.y, l.y);
  split2(e2 * inv, h.z, l.z); split2(e3 * inv, h.w, l.w);
  *(short4*)&oh[(size_t)row * 256 + lane * 4] = h;
  *(short4*)&ol[(size_t)row * 256 + lane * 4] = l;
}

// --- logits: [32,2048] split bf16 @ W3[2048,3] + b3 -> out[32,3] fp32 ---
__global__ __launch_bounds__(128) void logits_kernel(
    const short* __restrict__ a2h, const short* __restrict__ a2l,
    const float* __restrict__ W3, const float* __restrict__ b3,
    float* __restrict__ out)
{
  int t = threadIdx.x;
  if (t >= 96) return;
  int b = t / 3, c = t % 3;
  float acc = b3[c];
  for (int k = 0; k < 2048; ++k) {
    float a = bf2f(a2h[b * 2048 + k]) + bf2f(a2l[b * 2048 + k]);
    acc += a * W3[k * 3 + c];
  }
  out[t] = acc;
}

extern "C" void kernel_launch(void* const* d_in, const int* in_sizes, int n_in,
                              void* d_out, int out_size, void* d_ws, size_t ws_size,
                              hipStream_t stream) {
  (void)in_sizes; (void)n_in; (void)out_size; (void)ws_size;
  const float* P   = (const float*)d_in[0];
  const float* H   = (const float*)d_in[1];
  const float* W_F = (const float*)d_in[2];
  const float* W_G = (const float*)d_in[3];
  const float* W1  = (const float*)d_in[4];
  const float* b1  = (const float*)d_in[5];
  const float* W2  = (const float*)d_in[6];
  const float* b2  = (const float*)d_in[7];
  const float* W3  = (const float*)d_in[8];
  const float* b3  = (const float*)d_in[9];
  float* out = (float*)d_out;

  char* wsp = (char*)d_ws;
  auto alloc = [&](size_t bytes) {
    char* p = wsp;
    wsp += (bytes + 255) & ~(size_t)255;
    return p;
  };
  // ~240 MB total (Fbuf region is reused twice; see below)
  short* Cat_h  = (short*)alloc(16384ull * 2048 * 2);   // 64 MB  [P|betas ; H|alphas]
  short* Cat_l  = (short*)alloc(16384ull * 2048 * 2);   // 64 MB
  short* Fbuf   = (short*)alloc(32ull * 1024 * 1024 * 2); // 64 MB multi-use region
  short* WFT_h  = (short*)alloc(1024ull * 1024 * 2);
  short* WFT_l  = (short*)alloc(1024ull * 1024 * 2);
  short* WGT_h  = (short*)alloc(2048ull * 2048 * 2);
  short* WGT_l  = (short*)alloc(2048ull * 2048 * 2);
  float* eijs   = (float*)alloc(32ull * 256 * 256 * 4);
  short* attn_h = (short*)alloc(32ull * 256 * 256 * 2);
  short* attn_l = (short*)alloc(32ull * 256 * 256 * 2);
  short* atnT_h = (short*)alloc(32ull * 256 * 256 * 2);
  short* atnT_l = (short*)alloc(32ull * 256 * 256 * 2);
  float* agg    = (float*)alloc(32ull * 4096 * 4);
  short* aggb_h = (short*)alloc(128ull * 4096 * 2);     // 128-row pad (M=32)
  short* aggb_l = (short*)alloc(128ull * 4096 * 2);
  short* a1_h   = (short*)alloc(128ull * 2048 * 2);
  short* a1_l   = (short*)alloc(128ull * 2048 * 2);
  short* a2_h   = (short*)alloc(128ull * 2048 * 2);
  short* a2_l   = (short*)alloc(128ull * 2048 * 2);

  // Fbuf phase 1: F planes (each 16384x1024 = 32 MB)
  short* F_h = Fbuf;
  short* F_l = Fbuf + 16384ull * 1024;
  // Fbuf phase 2 (after E GEMM): P^T/H^T planes (each 32x1024x256 = 16 MB)
  short* PbT_h = Fbuf;
  short* PbT_l = Fbuf +  8ull * 1024 * 1024;
  short* HbT_h = Fbuf + 16ull * 1024 * 1024;
  short* HbT_l = Fbuf + 24ull * 1024 * 1024;
  // Fbuf phase 3 (after betas/alphas): W1^T (32 MB) + W2^T (16 MB) planes
  short* W1T_h = Fbuf;
  short* W1T_l = Fbuf +  8ull * 1024 * 1024;
  short* W2T_h = Fbuf + 16ull * 1024 * 1024;
  short* W2T_l = Fbuf + 20ull * 1024 * 1024;

  // 1. inputs -> split bf16 into Cat left halves; split-transposed weights
  conv_split<<<8192, 256, 0, stream>>>(P, Cat_h, Cat_l, 1024, 2048);
  conv_split<<<8192, 256, 0, stream>>>(H, Cat_h + 8192ull * 2048, Cat_l + 8192ull * 2048, 1024, 2048);
  transpose_split<<<dim3(32, 32, 1), 256, 0, stream>>>(W_F, WFT_h, WFT_l, 1024, 1024, 0, 0);
  transpose_split<<<dim3(64, 64, 1), 256, 0, stream>>>(W_G, WGT_h, WGT_l, 2048, 2048, 0, 0);

  // 2. F = tanh([P;H] @ W_F): A = Cat left half (lda=2048), split store
  gemm_nt_split<1, 1><<<dim3(128, 8, 1), 256, 0, stream>>>(
      Cat_h, Cat_l, 2048, 0, WFT_h, WFT_l, 1024, 0,
      F_h, F_l, 1024, 0, nullptr, 16384, 1024, nullptr);

  // 3. scores E[z] = F_p[z] @ F_h[z]^T (fp32 out)
  gemm_nt_split<0, 0><<<dim3(2, 2, 32), 256, 0, stream>>>(
      F_h, F_l, 1024, 256 * 1024,
      F_h + 8192ull * 1024, F_l + 8192ull * 1024, 1024, 256 * 1024,
      eijs, nullptr, 256, 65536, nullptr, 256, 1024, nullptr);

  // 4. softmax rows -> split attn; transpose planes; build P^T/H^T (into Fbuf)
  softmax_rows<<<2048, 256, 0, stream>>>(eijs, attn_h, attn_l);
  transpose_b2b<<<dim3(8, 8, 32), 256, 0, stream>>>(attn_h, atnT_h, 256, 256, 65536, 65536);
  transpose_b2b<<<dim3(8, 8, 32), 256, 0, stream>>>(attn_l, atnT_l, 256, 256, 65536, 65536);
  transpose_split<<<dim3(32, 8, 32), 256, 0, stream>>>(P, PbT_h, PbT_l, 256, 1024, 256 * 1024, 1024 * 256);
  transpose_split<<<dim3(32, 8, 32), 256, 0, stream>>>(H, HbT_h, HbT_l, 256, 1024, 256 * 1024, 1024 * 256);

  // 5. betas = attn @ H -> Cat1 right half; alphas = attn^T @ P -> Cat2 right half
  gemm_nt_split<0, 1><<<dim3(2, 8, 32), 256, 0, stream>>>(
      attn_h, attn_l, 256, 65536, HbT_h, HbT_l, 256, 1024 * 256,
      Cat_h + 1024, Cat_l + 1024, 2048, 256 * 2048, nullptr, 256, 256, nullptr);
  gemm_nt_split<0, 1><<<dim3(2, 8, 32), 256, 0, stream>>>(
      atnT_h, atnT_l, 256, 65536, PbT_h, PbT_l, 256, 1024 * 256,
      Cat_h + 8192ull * 2048 + 1024, Cat_l + 8192ull * 2048 + 1024, 2048, 256 * 2048,
      nullptr, 256, 256, nullptr);

  // 6. V = tanh(Cat @ W_G), fused column-sum over L -> agg[32][4096]
  zero_f32<<<512, 256, 0, stream>>>(agg, 32 * 4096);
  gemm_nt_split<1, 2><<<dim3(128, 16, 1), 256, 0, stream>>>(
      Cat_h, Cat_l, 2048, 0, WGT_h, WGT_l, 2048, 0,
      nullptr, nullptr, 0, 0, nullptr, 16384, 2048, agg);

  // 7. classifier (M=32 padded to 128; pad rows read finite 0xAA poison)
  transpose_split<<<dim3(64, 128, 1), 256, 0, stream>>>(W1, W1T_h, W1T_l, 4096, 2048, 0, 0);
  transpose_split<<<dim3(64, 64, 1),  256, 0, stream>>>(W2, W2T_h, W2T_l, 2048, 2048, 0, 0);
  conv_split<<<128, 256, 0, stream>>>(agg, aggb_h, aggb_l, 4096, 4096);
  gemm_nt_split<1, 1><<<dim3(1, 16, 1), 256, 0, stream>>>(
      aggb_h, aggb_l, 4096, 0, W1T_h, W1T_l, 4096, 0,
      a1_h, a1_l, 2048, 0, b1, 32, 4096, nullptr);
  gemm_nt_split<1, 1><<<dim3(1, 16, 1), 256, 0, stream>>>(
      a1_h, a1_l, 2048, 0, W2T_h, W2T_l, 2048, 0,
      a2_h, a2_l, 2048, 0, b2, 32, 2048, nullptr);
  logits_kernel<<<1, 128, 0, stream>>>(a2_h, a2_l, W3, b3, out);
}

// Round 3
// 708.932 us; speedup vs baseline: 1.7596x; 1.7596x over previous
//
#include <hip/hip_runtime.h>
#include <hip/hip_bf16.h>
#include <stdint.h>

// Shapes: B=32, L=256, D=1024, ALIGN=1024, FF=2048, NC=3
// Precision plan:
//  - F proj, E scores, attn, betas/alphas, classifier: bf16x3 split (~fp32)
//  - V = tanh(Cat@W_G) (the 137 GF hog): single-pass fp16 MFMA with
//    global_load_lds staging + XOR-swizzled LDS (m97-class structure).
//    fp16 single error contribution ~2.5e-3 on logits (bf16-single was ~0.02).

typedef __attribute__((ext_vector_type(8))) short    short8_t;   // 8 bf16
typedef __attribute__((ext_vector_type(4))) float    float4_t;
typedef __attribute__((ext_vector_type(8))) _Float16 half8_t;
typedef __attribute__((ext_vector_type(4))) _Float16 half4_t;

#define DEVI static __device__ __forceinline__

DEVI short f2bf(float f) {
  union { float f; unsigned u; } v; v.f = f;
  unsigned r = v.u + 0x7fffu + ((v.u >> 16) & 1u);   // RNE
  return (short)(r >> 16);
}
DEVI float bf2f(short s) {
  union { unsigned u; float f; } v;
  v.u = ((unsigned)(unsigned short)s) << 16;
  return v.f;
}
DEVI void split2(float x, short& hi, short& lo) {
  hi = f2bf(x);
  lo = f2bf(x - bf2f(hi));
}
DEVI float fast_tanh(float x) {
  float e = __expf(2.0f * x);
  return 1.0f - 2.0f / (e + 1.0f);
}
DEVI void gload16(const void* g, void* l) {
  // async global->LDS, 16B/lane; LDS dest = wave-uniform base + lane*16
  __builtin_amdgcn_global_load_lds(
      (const __attribute__((address_space(1))) void*)g,
      (__attribute__((address_space(3))) void*)l, 16, 0, 0);
}

// ---------------------------------------------------------------------------
// Split-bf16 NT GEMM (A=Ah+Al, B=Bh+Bl), 128x128 tile, BK=32, 4 waves,
// 3 MFMAs per product (hh,hl,lh). blockIdx.z = batch*kslices + kslice.
// OUT_MODE: 0 = fp32 atomicAdd (split-K accumulation; C must be pre-zeroed)
//           1 = split bf16 store (optional tanh)
//           4 = fp16 store
// ---------------------------------------------------------------------------
template <int DO_TANH, int OUT_MODE>
__global__ __launch_bounds__(256) void gemm_nt_split(
    const short* __restrict__ Ah, const short* __restrict__ Al, int lda, long sA,
    const short* __restrict__ Bh, const short* __restrict__ Bl, int ldb, long sB,
    void* __restrict__ Ch, void* __restrict__ Cl, int ldc, long sC,
    int M, int K, int kslices)
{
  __shared__ __align__(16) short Ash[128][40];
  __shared__ __align__(16) short Asl[128][40];
  __shared__ __align__(16) short Bsh[128][40];
  __shared__ __align__(16) short Bsl[128][40];

  const int z  = blockIdx.z;
  const int zb = z / kslices;            // batch index
  const int zk = z - zb * kslices;       // k-slice index
  const int Ksub = K / kslices;
  const int kbeg = zk * Ksub, kend = kbeg + Ksub;

  Ah += (size_t)zb * sA;  Al += (size_t)zb * sA;
  Bh += (size_t)zb * sB;  Bl += (size_t)zb * sB;

  const int row0 = blockIdx.x * 128;
  const int col0 = blockIdx.y * 128;

  const int t    = threadIdx.x;
  const int lane = t & 63;
  const int wave = t >> 6;
  const int wr = wave >> 1, wc = wave & 1;
  const int m15 = lane & 15, q = lane >> 4;

  float4_t acc[4][4];
#pragma unroll
  for (int i = 0; i < 4; ++i)
#pragma unroll
    for (int j = 0; j < 4; ++j) acc[i][j] = (float4_t)0.0f;

  for (int k0 = kbeg; k0 < kend; k0 += 32) {
#pragma unroll
    for (int i = 0; i < 2; ++i) {
      int c  = t + 256 * i;       // 0..511
      int r  = c >> 2;            // 0..127
      int kc = (c & 3) << 3;      // 0,8,16,24
      size_t ao = (size_t)(row0 + r) * lda + k0 + kc;
      size_t bo = (size_t)(col0 + r) * ldb + k0 + kc;
      *(int4*)(&Ash[r][kc]) = *(const int4*)(Ah + ao);
      *(int4*)(&Asl[r][kc]) = *(const int4*)(Al + ao);
      *(int4*)(&Bsh[r][kc]) = *(const int4*)(Bh + bo);
      *(int4*)(&Bsl[r][kc]) = *(const int4*)(Bl + bo);
    }
    __syncthreads();

    short8_t ah[4], al[4];
#pragma unroll
    for (int i = 0; i < 4; ++i) {
      ah[i] = *(const short8_t*)(&Ash[wr * 64 + i * 16 + m15][q * 8]);
      al[i] = *(const short8_t*)(&Asl[wr * 64 + i * 16 + m15][q * 8]);
    }
#pragma unroll
    for (int j = 0; j < 4; ++j) {
      short8_t bh = *(const short8_t*)(&Bsh[wc * 64 + j * 16 + m15][q * 8]);
      short8_t bl = *(const short8_t*)(&Bsl[wc * 64 + j * 16 + m15][q * 8]);
#pragma unroll
      for (int i = 0; i < 4; ++i) {
        acc[i][j] = __builtin_amdgcn_mfma_f32_16x16x32_bf16(ah[i], bh, acc[i][j], 0, 0, 0);
        acc[i][j] = __builtin_amdgcn_mfma_f32_16x16x32_bf16(ah[i], bl, acc[i][j], 0, 0, 0);
        acc[i][j] = __builtin_amdgcn_mfma_f32_16x16x32_bf16(al[i], bh, acc[i][j], 0, 0, 0);
      }
    }
    __syncthreads();
  }

  short*    Chs = (short*)Ch    + (size_t)zb * sC;
  short*    Cls = (short*)Cl    + (size_t)zb * sC;
  float*    Cf  = (float*)Ch    + (size_t)zb * sC;
  _Float16* C16 = (_Float16*)Ch + (size_t)zb * sC;
#pragma unroll
  for (int i = 0; i < 4; ++i) {
#pragma unroll
    for (int r = 0; r < 4; ++r) {
      int gm = row0 + wr * 64 + i * 16 + q * 4 + r;
      if (gm < M) {
#pragma unroll
        for (int j = 0; j < 4; ++j) {
          int gn = col0 + wc * 64 + j * 16 + m15;
          float v = acc[i][j][r];
          if (DO_TANH) v = fast_tanh(v);
          if (OUT_MODE == 0) {
            atomicAdd(&Cf[(size_t)gm * ldc + gn], v);
          } else if (OUT_MODE == 1) {
            short hi, lo; split2(v, hi, lo);
            Chs[(size_t)gm * ldc + gn] = hi;
            Cls[(size_t)gm * ldc + gn] = lo;
          } else {
            C16[(size_t)gm * ldc + gn] = (_Float16)v;
          }
        }
      }
    }
  }
}

// ---------------------------------------------------------------------------
// fp16 single-pass NT GEMM with fused tanh + column-sum -> agg.
// m97-class: global_load_lds width=16, unpadded [128][32] LDS tiles with
// XOR chunk swizzle (chunk c of row r stored at slot c ^ ((r>>1)&3)) so that
// ds_read_b128 fragment reads are exactly 2-way bank-aliased (free).
// Used for V: M=16384 rows = [Cat1;Cat2], 256 rows/batch, agg[32][4096].
// ---------------------------------------------------------------------------
__global__ __launch_bounds__(256) void gemm_f16_colsum(
    const _Float16* __restrict__ A, int lda,
    const _Float16* __restrict__ B, int ldb,
    int K, float* __restrict__ agg)
{
  __shared__ __align__(16) _Float16 As[128 * 32];
  __shared__ __align__(16) _Float16 Bs[128 * 32];

  const int row0 = blockIdx.x * 128;
  const int col0 = blockIdx.y * 128;
  const int t = threadIdx.x, lane = t & 63, wave = t >> 6;
  const int wr = wave >> 1, wc = wave & 1;
  const int m15 = lane & 15, q = lane >> 4;

  // staging: wave w stages rows [w*32, w*32+32) of both tiles, 16 rows/call.
  // lane l -> row base+(l>>2), LDS slot l&3; global chunk = (l&3)^((l>>3)&3).
  const int srow = wave * 32 + (lane >> 2);
  const int cg   = ((lane & 3) ^ ((lane >> 3) & 3)) * 8;
  const _Float16* ga0 = A + (size_t)(row0 + srow) * lda + cg;
  const _Float16* ga1 = ga0 + (size_t)16 * lda;
  const _Float16* gb0 = B + (size_t)(col0 + srow) * ldb + cg;
  const _Float16* gb1 = gb0 + (size_t)16 * ldb;
  _Float16* lA0 = &As[(wave * 32) * 32];
  _Float16* lA1 = &As[(wave * 32 + 16) * 32];
  _Float16* lB0 = &Bs[(wave * 32) * 32];
  _Float16* lB1 = &Bs[(wave * 32 + 16) * 32];

  // fragment LDS offsets (loop-invariant): row R0+m15, want chunk q at slot
  // q ^ ((m15>>1)&3)  (R0 multiple of 16 drops out of (row>>1)&3)
  const int fs = (q ^ ((m15 >> 1) & 3)) * 8;
  int aoff[4], boff[4];
#pragma unroll
  for (int i = 0; i < 4; ++i) {
    aoff[i] = (wr * 64 + i * 16 + m15) * 32 + fs;
    boff[i] = (wc * 64 + i * 16 + m15) * 32 + fs;
  }

  float4_t acc[4][4];
#pragma unroll
  for (int i = 0; i < 4; ++i)
#pragma unroll
    for (int j = 0; j < 4; ++j) acc[i][j] = (float4_t)0.0f;

  for (int k0 = 0; k0 < K; k0 += 32) {
    gload16(ga0, lA0);
    gload16(ga1, lA1);
    gload16(gb0, lB0);
    gload16(gb1, lB1);
    ga0 += 32; ga1 += 32; gb0 += 32; gb1 += 32;
    __syncthreads();

    half8_t af[4], bfr[4];
#pragma unroll
    for (int i = 0; i < 4; ++i) af[i]  = *(const half8_t*)&As[aoff[i]];
#pragma unroll
    for (int j = 0; j < 4; ++j) bfr[j] = *(const half8_t*)&Bs[boff[j]];
#pragma unroll
    for (int i = 0; i < 4; ++i)
#pragma unroll
      for (int j = 0; j < 4; ++j)
        acc[i][j] = __builtin_amdgcn_mfma_f32_16x16x32_f16(af[i], bfr[j], acc[i][j], 0, 0, 0);
    __syncthreads();
  }

  // epilogue: tanh + column-sum into agg[b][half*2048 + col]
  const int half_ = row0 >= 8192;
  const int b     = (row0 & 8191) >> 8;
#pragma unroll
  for (int j = 0; j < 4; ++j) {
    float s = 0.0f;
#pragma unroll
    for (int i = 0; i < 4; ++i)
#pragma unroll
      for (int r = 0; r < 4; ++r) s += fast_tanh(acc[i][j][r]);
    s += __shfl_xor(s, 16);
    s += __shfl_xor(s, 32);
    if (q == 0) {
      int col = col0 + wc * 64 + j * 16 + m15;
      atomicAdd(&agg[(size_t)b * 4096 + half_ * 2048 + col], s);
    }
  }
}

// --- fp32 -> split bf16 transpose (batched): out[z][c][r] ---
__global__ __launch_bounds__(256) void transpose_split(
    const float* __restrict__ in, short* __restrict__ oh, short* __restrict__ ol,
    int R, int C, long sIn, long sOut)
{
  __shared__ float tile[32][33];
  in += (size_t)blockIdx.z * sIn;
  oh += (size_t)blockIdx.z * sOut;
  ol += (size_t)blockIdx.z * sOut;
  const int tx = threadIdx.x & 31, ty = threadIdx.x >> 5;
  const int c0 = blockIdx.x * 32, r0 = blockIdx.y * 32;
#pragma unroll
  for (int i = 0; i < 4; ++i) {
    int r = ty + i * 8;
    tile[r][tx] = in[(size_t)(r0 + r) * C + c0 + tx];
  }
  __syncthreads();
#pragma unroll
  for (int i = 0; i < 4; ++i) {
    int cc = ty + i * 8;
    float v = tile[tx][cc];
    short hi, lo; split2(v, hi, lo);
    size_t o = (size_t)(c0 + cc) * R + r0 + tx;
    oh[o] = hi;
    ol[o] = lo;
  }
}

// --- fp32 -> fp16 transpose: out[c][r] ---
__global__ __launch_bounds__(256) void transpose_f16(
    const float* __restrict__ in, _Float16* __restrict__ out, int R, int C)
{
  __shared__ float tile[32][33];
  const int tx = threadIdx.x & 31, ty = threadIdx.x >> 5;
  const int c0 = blockIdx.x * 32, r0 = blockIdx.y * 32;
#pragma unroll
  for (int i = 0; i < 4; ++i) {
    int r = ty + i * 8;
    tile[r][tx] = in[(size_t)(r0 + r) * C + c0 + tx];
  }
  __syncthreads();
#pragma unroll
  for (int i = 0; i < 4; ++i) {
    int cc = ty + i * 8;
    out[(size_t)(c0 + cc) * R + r0 + tx] = (_Float16)tile[tx][cc];
  }
}

// --- bf16 -> bf16 transpose (batched), for attn planes ---
__global__ __launch_bounds__(256) void transpose_b2b(
    const short* __restrict__ in, short* __restrict__ out,
    int R, int C, long sIn, long sOut)
{
  __shared__ short tile[32][33];
  in  += (size_t)blockIdx.z * sIn;
  out += (size_t)blockIdx.z * sOut;
  const int tx = threadIdx.x & 31, ty = threadIdx.x >> 5;
  const int c0 = blockIdx.x * 32, r0 = blockIdx.y * 32;
#pragma unroll
  for (int i = 0; i < 4; ++i) {
    int r = ty + i * 8;
    tile[r][tx] = in[(size_t)(r0 + r) * C + c0 + tx];
  }
  __syncthreads();
#pragma unroll
  for (int i = 0; i < 4; ++i) {
    int cc = ty + i * 8;
    out[(size_t)(c0 + cc) * R + r0 + tx] = tile[tx][cc];
  }
}

// --- input conv: fp32 [8192x1024] -> split bf16 planes + fp16 Cat half ---
__global__ __launch_bounds__(256) void conv_in(
    const float* __restrict__ in, short* __restrict__ oh, short* __restrict__ ol,
    _Float16* __restrict__ cat)
{
  size_t i = ((size_t)blockIdx.x * 256 + threadIdx.x) * 4;
  float4 v = *(const float4*)&in[i];
  short4 h, l;
  split2(v.x, h.x, l.x); split2(v.y, h.y, l.y);
  split2(v.z, h.z, l.z); split2(v.w, h.w, l.w);
  *(short4*)&oh[i] = h;
  *(short4*)&ol[i] = l;
  size_t row = i >> 10;
  int col    = (int)(i & 1023);
  half4_t c16;
  c16.x = (_Float16)v.x; c16.y = (_Float16)v.y;
  c16.z = (_Float16)v.z; c16.w = (_Float16)v.w;
  *(half4_t*)&cat[row * 2048 + col] = c16;
}

// --- fp32 -> split bf16 (contiguous rows, strided out) ---
__global__ __launch_bounds__(256) void conv_split(
    const float* __restrict__ in, short* __restrict__ oh, short* __restrict__ ol,
    int row_len, int out_stride)
{
  size_t i = ((size_t)blockIdx.x * 256 + threadIdx.x) * 4;
  float4 v = *(const float4*)&in[i];
  size_t row = i / (unsigned)row_len;
  int col    = (int)(i - row * row_len);
  size_t o = row * out_stride + col;
  short4 h, l;
  split2(v.x, h.x, l.x); split2(v.y, h.y, l.y);
  split2(v.z, h.z, l.z); split2(v.w, h.w, l.w);
  *(short4*)&oh[o] = h;
  *(short4*)&ol[o] = l;
}

__global__ __launch_bounds__(256) void zero_f32(float* __restrict__ p, int n)
{
  int i = blockIdx.x * 256 + threadIdx.x;
  if (i < n) p[i] = 0.0f;
}

// --- softmax over rows of 256 (one wave per row), fp32 -> split bf16 ---
__global__ __launch_bounds__(256) void softmax_rows(
    const float* __restrict__ e, short* __restrict__ oh, short* __restrict__ ol)
{
  const int row  = blockIdx.x * 4 + (threadIdx.x >> 6);
  const int lane = threadIdx.x & 63;
  const float4 v = *(const float4*)&e[(size_t)row * 256 + lane * 4];
  float m = fmaxf(fmaxf(v.x, v.y), fmaxf(v.z, v.w));
#pragma unroll
  for (int off = 32; off; off >>= 1) m = fmaxf(m, __shfl_xor(m, off));
  float e0 = __expf(v.x - m), e1 = __expf(v.y - m);
  float e2 = __expf(v.z - m), e3 = __expf(v.w - m);
  float s = e0 + e1 + e2 + e3;
#pragma unroll
  for (int off = 32; off; off >>= 1) s += __shfl_xor(s, off);
  float inv = 1.0f / s;
  short4 h, l;
  split2(e0 * inv, h.x, l.x); split2(e1 * inv, h.y, l.y);
  split2(e2 * inv, h.z, l.z); split2(e3 * inv, h.w, l.w);
  *(short4*)&oh[(size_t)row * 256 + lane * 4] = h;
  *(short4*)&ol[(size_t)row * 256 + lane * 4] = l;
}

// --- a1 = tanh(c + bias) -> split bf16 ---
__global__ __launch_bounds__(256) void bias_tanh_split(
    const float* __restrict__ c, const float* __restrict__ bias,
    short* __restrict__ oh, short* __restrict__ ol, int n)
{
  int i = blockIdx.x * 256 + threadIdx.x;
  if (i < n) {
    float v = fast_tanh(c[i] + bias[i & 2047]);
    short hi, lo; split2(v, hi, lo);
    oh[i] = hi;
    ol[i] = lo;
  }
}

// --- logits: block b: out[b][0..2] = tanh(c2f[b]+b2) @ W3 + b3 ---
__global__ __launch_bounds__(256) void logits2(
    const float* __restrict__ c2f, const float* __restrict__ b2,
    const float* __restrict__ W3, const float* __restrict__ b3,
    float* __restrict__ out)
{
  const int b = blockIdx.x, t = threadIdx.x;
  float p0 = 0.f, p1 = 0.f, p2 = 0.f;
  for (int k = t; k < 2048; k += 256) {
    float a = fast_tanh(c2f[b * 2048 + k] + b2[k]);
    p0 += a * W3[k * 3 + 0];
    p1 += a * W3[k * 3 + 1];
    p2 += a * W3[k * 3 + 2];
  }
#pragma unroll
  for (int off = 32; off; off >>= 1) {
    p0 += __shfl_xor(p0, off);
    p1 += __shfl_xor(p1, off);
    p2 += __shfl_xor(p2, off);
  }
  __shared__ float red[4][3];
  if ((t & 63) == 0) {
    red[t >> 6][0] = p0; red[t >> 6][1] = p1; red[t >> 6][2] = p2;
  }
  __syncthreads();
  if (t < 3) out[b * 3 + t] = b3[t] + red[0][t] + red[1][t] + red[2][t] + red[3][t];
}

extern "C" void kernel_launch(void* const* d_in, const int* in_sizes, int n_in,
                              void* d_out, int out_size, void* d_ws, size_t ws_size,
                              hipStream_t stream) {
  (void)in_sizes; (void)n_in; (void)out_size; (void)ws_size;
  const float* P   = (const float*)d_in[0];
  const float* H   = (const float*)d_in[1];
  const float* W_F = (const float*)d_in[2];
  const float* W_G = (const float*)d_in[3];
  const float* W1  = (const float*)d_in[4];
  const float* b1  = (const float*)d_in[5];
  const float* W2  = (const float*)d_in[6];
  const float* b2  = (const float*)d_in[7];
  const float* W3  = (const float*)d_in[8];
  const float* b3  = (const float*)d_in[9];
  float* out = (float*)d_out;

  char* wsp = (char*)d_ws;
  auto alloc = [&](size_t bytes) {
    char* p = wsp;
    wsp += (bytes + 255) & ~(size_t)255;
    return p;
  };
  // ~244 MB total
  short*    Pp_h  = (short*)alloc(16384ull * 1024 * 2);    // [P;H] split planes
  short*    Pp_l  = (short*)alloc(16384ull * 1024 * 2);
  _Float16* Cat16 = (_Float16*)alloc(16384ull * 2048 * 2); // [P|betas ; H|alphas]
  short*    Fbuf  = (short*)alloc(32ull * 1024 * 1024 * 2); // 64 MB multi-use
  short*    WFT_h = (short*)alloc(1024ull * 1024 * 2);
  short*    WFT_l = (short*)alloc(1024ull * 1024 * 2);
  _Float16* WGT16 = (_Float16*)alloc(2048ull * 2048 * 2);
  float*    eijs  = (float*)alloc(32ull * 256 * 256 * 4);
  short*    attn_h= (short*)alloc(32ull * 256 * 256 * 2);
  short*    attn_l= (short*)alloc(32ull * 256 * 256 * 2);
  short*    atnT_h= (short*)alloc(32ull * 256 * 256 * 2);
  short*    atnT_l= (short*)alloc(32ull * 256 * 256 * 2);
  float*    agg   = (float*)alloc(32ull * 4096 * 4);
  short*    aggb_h= (short*)alloc(128ull * 4096 * 2);      // 128-row pad (M=32)
  short*    aggb_l= (short*)alloc(128ull * 4096 * 2);
  float*    c1f   = (float*)alloc(32ull * 2048 * 4);
  float*    c2f   = (float*)alloc(32ull * 2048 * 4);
  short*    a1_h  = (short*)alloc(128ull * 2048 * 2);
  short*    a1_l  = (short*)alloc(128ull * 2048 * 2);

  // Fbuf phase 1: F planes (2 x 32 MB)
  short* F_h = Fbuf;
  short* F_l = Fbuf + 16384ull * 1024;
  // Fbuf phase 2: P^T/H^T planes (4 x 16 MB)
  short* PbT_h = Fbuf;
  short* PbT_l = Fbuf +  8ull * 1024 * 1024;
  short* HbT_h = Fbuf + 16ull * 1024 * 1024;
  short* HbT_l = Fbuf + 24ull * 1024 * 1024;
  // Fbuf phase 3: W1^T (2 x 16 MB) + W2^T (2 x 8 MB) planes
  short* W1T_h = Fbuf;
  short* W1T_l = Fbuf +  8ull * 1024 * 1024;
  short* W2T_h = Fbuf + 16ull * 1024 * 1024;
  short* W2T_l = Fbuf + 20ull * 1024 * 1024;

  // 1. input conversions
  conv_in<<<8192, 256, 0, stream>>>(P, Pp_h, Pp_l, Cat16);
  conv_in<<<8192, 256, 0, stream>>>(H, Pp_h + 8192ull * 1024, Pp_l + 8192ull * 1024,
                                    Cat16 + 8192ull * 2048);
  transpose_split<<<dim3(32, 32, 1), 256, 0, stream>>>(W_F, WFT_h, WFT_l, 1024, 1024, 0, 0);
  transpose_f16<<<dim3(64, 64, 1), 256, 0, stream>>>(W_G, WGT16, 2048, 2048);

  // 2. F = tanh([P;H] @ W_F), split store into Fbuf
  gemm_nt_split<1, 1><<<dim3(128, 8, 1), 256, 0, stream>>>(
      Pp_h, Pp_l, 1024, 0, WFT_h, WFT_l, 1024, 0,
      F_h, F_l, 1024, 0, 16384, 1024, 1);

  // 3. scores E[z] = F_p[z] @ F_h[z]^T, split-K x4 (atomic fp32)
  zero_f32<<<8192, 256, 0, stream>>>(eijs, 32 * 256 * 256);
  gemm_nt_split<0, 0><<<dim3(2, 2, 128), 256, 0, stream>>>(
      F_h, F_l, 1024, 256 * 1024,
      F_h + 8192ull * 1024, F_l + 8192ull * 1024, 1024, 256 * 1024,
      eijs, nullptr, 256, 65536, 256, 1024, 4);

  // 4. softmax -> split attn; transposed planes; P^T/H^T into Fbuf
  softmax_rows<<<2048, 256, 0, stream>>>(eijs, attn_h, attn_l);
  transpose_b2b<<<dim3(8, 8, 32), 256, 0, stream>>>(attn_h, atnT_h, 256, 256, 65536, 65536);
  transpose_b2b<<<dim3(8, 8, 32), 256, 0, stream>>>(attn_l, atnT_l, 256, 256, 65536, 65536);
  transpose_split<<<dim3(32, 8, 32), 256, 0, stream>>>(P, PbT_h, PbT_l, 256, 1024, 256 * 1024, 1024 * 256);
  transpose_split<<<dim3(32, 8, 32), 256, 0, stream>>>(H, HbT_h, HbT_l, 256, 1024, 256 * 1024, 1024 * 256);

  // 5. betas/alphas (split GEMM, fp16 store into Cat16 right halves)
  gemm_nt_split<0, 4><<<dim3(2, 8, 32), 256, 0, stream>>>(
      attn_h, attn_l, 256, 65536, HbT_h, HbT_l, 256, 1024 * 256,
      Cat16 + 1024, nullptr, 2048, 256 * 2048, 256, 256, 1);
  gemm_nt_split<0, 4><<<dim3(2, 8, 32), 256, 0, stream>>>(
      atnT_h, atnT_l, 256, 65536, PbT_h, PbT_l, 256, 1024 * 256,
      Cat16 + 8192ull * 2048 + 1024, nullptr, 2048, 256 * 2048, 256, 256, 1);

  // 6. V = tanh(Cat @ W_G) fused column-sum -> agg (fp16 single-pass, async LDS)
  zero_f32<<<512, 256, 0, stream>>>(agg, 32 * 4096);
  gemm_f16_colsum<<<dim3(128, 16, 1), 256, 0, stream>>>(
      Cat16, 2048, WGT16, 2048, 2048, agg);

  // 7. classifier: split-K split-bf16 GEMMs + epilogues
  transpose_split<<<dim3(64, 128, 1), 256, 0, stream>>>(W1, W1T_h, W1T_l, 4096, 2048, 0, 0);
  transpose_split<<<dim3(64, 64, 1),  256, 0, stream>>>(W2, W2T_h, W2T_l, 2048, 2048, 0, 0);
  conv_split<<<128, 256, 0, stream>>>(agg, aggb_h, aggb_l, 4096, 4096);
  zero_f32<<<256, 256, 0, stream>>>(c1f, 32 * 2048);
  gemm_nt_split<0, 0><<<dim3(1, 16, 8), 256, 0, stream>>>(
      aggb_h, aggb_l, 4096, 0, W1T_h, W1T_l, 4096, 0,
      c1f, nullptr, 2048, 0, 32, 4096, 8);
  bias_tanh_split<<<256, 256, 0, stream>>>(c1f, b1, a1_h, a1_l, 32 * 2048);
  zero_f32<<<256, 256, 0, stream>>>(c2f, 32 * 2048);
  gemm_nt_split<0, 0><<<dim3(1, 16, 4), 256, 0, stream>>>(
      a1_h, a1_l, 2048, 0, W2T_h, W2T_l, 2048, 0,
      c2f, nullptr, 2048, 0, 32, 2048, 4);
  logits2<<<32, 256, 0, stream>>>(c2f, b2, W3, b3, out);
}

// Round 4
// 643.523 us; speedup vs baseline: 1.9384x; 1.1016x over previous
//
#include <hip/hip_runtime.h>
#include <hip/hip_bf16.h>
#include <stdint.h>

// Shapes: B=32, L=256, D=1024, ALIGN=1024, FF=2048, NC=3
// Precision plan:
//  - F proj (split bf16x3), E scores (split bf16x3): the softmax-sensitive path
//  - attn, betas/alphas: fp16 single (output is fp16 anyway; store rounding
//    dominates), V = tanh(Cat@W_G): fp16 single + fused colsum
//  - classifier: split bf16x3 (cheap, keeps margin)

typedef __attribute__((ext_vector_type(8))) short    short8_t;   // 8 bf16
typedef __attribute__((ext_vector_type(4))) float    float4_t;
typedef __attribute__((ext_vector_type(8))) _Float16 half8_t;
typedef __attribute__((ext_vector_type(4))) _Float16 half4_t;

#define DEVI static __device__ __forceinline__

DEVI short f2bf(float f) {
  union { float f; unsigned u; } v; v.f = f;
  unsigned r = v.u + 0x7fffu + ((v.u >> 16) & 1u);   // RNE
  return (short)(r >> 16);
}
DEVI float bf2f(short s) {
  union { unsigned u; float f; } v;
  v.u = ((unsigned)(unsigned short)s) << 16;
  return v.f;
}
DEVI void split2(float x, short& hi, short& lo) {
  hi = f2bf(x);
  lo = f2bf(x - bf2f(hi));
}
DEVI float fast_tanh(float x) {
  float e = __expf(2.0f * x);
  return 1.0f - 2.0f / (e + 1.0f);
}
DEVI void gload16(const void* g, void* l) {
  // async global->LDS, 16B/lane; LDS dest = wave-uniform base + lane*16
  __builtin_amdgcn_global_load_lds(
      (const __attribute__((address_space(1))) void*)g,
      (__attribute__((address_space(3))) void*)l, 16, 0, 0);
}

// ---------------------------------------------------------------------------
// Split-bf16 NT GEMM (A=Ah+Al, B=Bh+Bl), 128x128 tile, BK=32, 4 waves,
// 3 MFMAs per product (hh,hl,lh). blockIdx.z = batch*kslices + kslice.
// OUT_MODE: 0 = fp32 atomicAdd (split-K accumulation; C pre-zeroed)
//           1 = split bf16 store (optional tanh)
// ---------------------------------------------------------------------------
template <int DO_TANH, int OUT_MODE>
__global__ __launch_bounds__(256) void gemm_nt_split(
    const short* __restrict__ Ah, const short* __restrict__ Al, int lda, long sA,
    const short* __restrict__ Bh, const short* __restrict__ Bl, int ldb, long sB,
    void* __restrict__ Ch, void* __restrict__ Cl, int ldc, long sC,
    int M, int K, int kslices)
{
  __shared__ __align__(16) short Ash[128][40];
  __shared__ __align__(16) short Asl[128][40];
  __shared__ __align__(16) short Bsh[128][40];
  __shared__ __align__(16) short Bsl[128][40];

  const int z  = blockIdx.z;
  const int zb = z / kslices;
  const int zk = z - zb * kslices;
  const int Ksub = K / kslices;
  const int kbeg = zk * Ksub, kend = kbeg + Ksub;

  Ah += (size_t)zb * sA;  Al += (size_t)zb * sA;
  Bh += (size_t)zb * sB;  Bl += (size_t)zb * sB;

  const int row0 = blockIdx.x * 128;
  const int col0 = blockIdx.y * 128;

  const int t    = threadIdx.x;
  const int lane = t & 63;
  const int wave = t >> 6;
  const int wr = wave >> 1, wc = wave & 1;
  const int m15 = lane & 15, q = lane >> 4;

  float4_t acc[4][4];
#pragma unroll
  for (int i = 0; i < 4; ++i)
#pragma unroll
    for (int j = 0; j < 4; ++j) acc[i][j] = (float4_t)0.0f;

  for (int k0 = kbeg; k0 < kend; k0 += 32) {
#pragma unroll
    for (int i = 0; i < 2; ++i) {
      int c  = t + 256 * i;       // 0..511
      int r  = c >> 2;            // 0..127
      int kc = (c & 3) << 3;      // 0,8,16,24
      size_t ao = (size_t)(row0 + r) * lda + k0 + kc;
      size_t bo = (size_t)(col0 + r) * ldb + k0 + kc;
      *(int4*)(&Ash[r][kc]) = *(const int4*)(Ah + ao);
      *(int4*)(&Asl[r][kc]) = *(const int4*)(Al + ao);
      *(int4*)(&Bsh[r][kc]) = *(const int4*)(Bh + bo);
      *(int4*)(&Bsl[r][kc]) = *(const int4*)(Bl + bo);
    }
    __syncthreads();

    short8_t ah[4], al[4];
#pragma unroll
    for (int i = 0; i < 4; ++i) {
      ah[i] = *(const short8_t*)(&Ash[wr * 64 + i * 16 + m15][q * 8]);
      al[i] = *(const short8_t*)(&Asl[wr * 64 + i * 16 + m15][q * 8]);
    }
#pragma unroll
    for (int j = 0; j < 4; ++j) {
      short8_t bh = *(const short8_t*)(&Bsh[wc * 64 + j * 16 + m15][q * 8]);
      short8_t bl = *(const short8_t*)(&Bsl[wc * 64 + j * 16 + m15][q * 8]);
#pragma unroll
      for (int i = 0; i < 4; ++i) {
        acc[i][j] = __builtin_amdgcn_mfma_f32_16x16x32_bf16(ah[i], bh, acc[i][j], 0, 0, 0);
        acc[i][j] = __builtin_amdgcn_mfma_f32_16x16x32_bf16(ah[i], bl, acc[i][j], 0, 0, 0);
        acc[i][j] = __builtin_amdgcn_mfma_f32_16x16x32_bf16(al[i], bh, acc[i][j], 0, 0, 0);
      }
    }
    __syncthreads();
  }

  short* Chs = (short*)Ch + (size_t)zb * sC;
  short* Cls = (short*)Cl + (size_t)zb * sC;
  float* Cf  = (float*)Ch + (size_t)zb * sC;
#pragma unroll
  for (int i = 0; i < 4; ++i) {
#pragma unroll
    for (int r = 0; r < 4; ++r) {
      int gm = row0 + wr * 64 + i * 16 + q * 4 + r;
      if (gm < M) {
#pragma unroll
        for (int j = 0; j < 4; ++j) {
          int gn = col0 + wc * 64 + j * 16 + m15;
          float v = acc[i][j][r];
          if (DO_TANH) v = fast_tanh(v);
          if (OUT_MODE == 0) {
            atomicAdd(&Cf[(size_t)gm * ldc + gn], v);
          } else {
            short hi, lo; split2(v, hi, lo);
            Chs[(size_t)gm * ldc + gn] = hi;
            Cls[(size_t)gm * ldc + gn] = lo;
          }
        }
      }
    }
  }
}

// ---------------------------------------------------------------------------
// fp16 single-pass NT GEMM, BK=64 (two 32-chunks per barrier pair), async
// global_load_lds staging, XOR chunk-swizzled unpadded LDS (0 bank conflicts).
// MODE 1: fp16 store (betas/alphas; batched via blockIdx.z, M = gridX*128)
// MODE 2: tanh + column-sum -> agg (V: 16384 rows = [Cat1;Cat2], agg[32][4096])
// K % 64 == 0.
// ---------------------------------------------------------------------------
template <int MODE>
__global__ __launch_bounds__(256) void gemm_f16(
    const _Float16* __restrict__ A, int lda, long sA,
    const _Float16* __restrict__ B, int ldb, long sB,
    _Float16* __restrict__ C, int ldc, long sC,
    int K, float* __restrict__ agg)
{
  __shared__ __align__(16) _Float16 As[2 * 128 * 32];
  __shared__ __align__(16) _Float16 Bs[2 * 128 * 32];

  const int z = blockIdx.z;
  A += (size_t)z * sA;
  B += (size_t)z * sB;

  const int row0 = blockIdx.x * 128;
  const int col0 = blockIdx.y * 128;
  const int t = threadIdx.x, lane = t & 63, wave = t >> 6;
  const int wr = wave >> 1, wc = wave & 1;
  const int m15 = lane & 15, q = lane >> 4;

  // staging: wave w stages rows [w*32, w*32+32), 16 rows per gload16 call.
  // lane l -> row base+(l>>2), LDS slot l&3; global chunk (l&3)^((l>>3)&3).
  const int srow = wave * 32 + (lane >> 2);
  const int cg   = ((lane & 3) ^ ((lane >> 3) & 3)) * 8;
  const _Float16* gA0 = A + (size_t)(row0 + srow) * lda + cg;        // chunk half 0
  const _Float16* gA1 = gA0 + (size_t)16 * lda;
  const _Float16* gB0 = B + (size_t)(col0 + srow) * ldb + cg;
  const _Float16* gB1 = gB0 + (size_t)16 * ldb;
  const _Float16* gA0b = gA0 + 32;                                    // chunk half 1
  const _Float16* gA1b = gA1 + 32;
  const _Float16* gB0b = gB0 + 32;
  const _Float16* gB1b = gB1 + 32;
  _Float16* lA0  = &As[(wave * 32) * 32];
  _Float16* lA1  = &As[(wave * 32 + 16) * 32];
  _Float16* lB0  = &Bs[(wave * 32) * 32];
  _Float16* lB1  = &Bs[(wave * 32 + 16) * 32];
  _Float16* lA0b = lA0 + 4096;
  _Float16* lA1b = lA1 + 4096;
  _Float16* lB0b = lB0 + 4096;
  _Float16* lB1b = lB1 + 4096;

  // fragment LDS offsets: row R+m15 wants chunk q at slot q ^ ((m15>>1)&3)
  const int fs = (q ^ ((m15 >> 1) & 3)) * 8;
  int aoff[4], boff[4];
#pragma unroll
  for (int i = 0; i < 4; ++i) {
    aoff[i] = (wr * 64 + i * 16 + m15) * 32 + fs;
    boff[i] = (wc * 64 + i * 16 + m15) * 32 + fs;
  }

  float4_t acc[4][4];
#pragma unroll
  for (int i = 0; i < 4; ++i)
#pragma unroll
    for (int j = 0; j < 4; ++j) acc[i][j] = (float4_t)0.0f;

  for (int k0 = 0; k0 < K; k0 += 64) {
    gload16(gA0, lA0);  gload16(gA1, lA1);
    gload16(gB0, lB0);  gload16(gB1, lB1);
    gload16(gA0b, lA0b); gload16(gA1b, lA1b);
    gload16(gB0b, lB0b); gload16(gB1b, lB1b);
    gA0 += 64; gA1 += 64; gB0 += 64; gB1 += 64;
    gA0b += 64; gA1b += 64; gB0b += 64; gB1b += 64;
    __syncthreads();

#pragma unroll
    for (int h = 0; h < 2; ++h) {
      half8_t af[4], bfr[4];
#pragma unroll
      for (int i = 0; i < 4; ++i) af[i]  = *(const half8_t*)&As[h * 4096 + aoff[i]];
#pragma unroll
      for (int j = 0; j < 4; ++j) bfr[j] = *(const half8_t*)&Bs[h * 4096 + boff[j]];
#pragma unroll
      for (int i = 0; i < 4; ++i)
#pragma unroll
        for (int j = 0; j < 4; ++j)
          acc[i][j] = __builtin_amdgcn_mfma_f32_16x16x32_f16(af[i], bfr[j], acc[i][j], 0, 0, 0);
    }
    __syncthreads();
  }

  if (MODE == 2) {
    // tanh + column-sum into agg[b][half*2048 + col]
    const int half_ = row0 >= 8192;
    const int b     = (row0 & 8191) >> 8;
#pragma unroll
    for (int j = 0; j < 4; ++j) {
      float s = 0.0f;
#pragma unroll
      for (int i = 0; i < 4; ++i)
#pragma unroll
        for (int r = 0; r < 4; ++r) s += fast_tanh(acc[i][j][r]);
      s += __shfl_xor(s, 16);
      s += __shfl_xor(s, 32);
      if (q == 0) {
        int col = col0 + wc * 64 + j * 16 + m15;
        atomicAdd(&agg[(size_t)b * 4096 + half_ * 2048 + col], s);
      }
    }
  } else {
    _Float16* Cp = C + (size_t)z * sC;
#pragma unroll
    for (int i = 0; i < 4; ++i)
#pragma unroll
      for (int r = 0; r < 4; ++r) {
        int gm = row0 + wr * 64 + i * 16 + q * 4 + r;
#pragma unroll
        for (int j = 0; j < 4; ++j) {
          int gn = col0 + wc * 64 + j * 16 + m15;
          Cp[(size_t)gm * ldc + gn] = (_Float16)acc[i][j][r];
        }
      }
  }
}

// --- fp32 -> split bf16 transpose: out[c][r] ---
__global__ __launch_bounds__(256) void transpose_split(
    const float* __restrict__ in, short* __restrict__ oh, short* __restrict__ ol,
    int R, int C)
{
  __shared__ float tile[32][33];
  const int tx = threadIdx.x & 31, ty = threadIdx.x >> 5;
  const int c0 = blockIdx.x * 32, r0 = blockIdx.y * 32;
#pragma unroll
  for (int i = 0; i < 4; ++i) {
    int r = ty + i * 8;
    tile[r][tx] = in[(size_t)(r0 + r) * C + c0 + tx];
  }
  __syncthreads();
#pragma unroll
  for (int i = 0; i < 4; ++i) {
    int cc = ty + i * 8;
    float v = tile[tx][cc];
    short hi, lo; split2(v, hi, lo);
    size_t o = (size_t)(c0 + cc) * R + r0 + tx;
    oh[o] = hi;
    ol[o] = lo;
  }
}

// --- fp32 -> fp16 transpose: out[c][r] ---
__global__ __launch_bounds__(256) void transpose_f16(
    const float* __restrict__ in, _Float16* __restrict__ out, int R, int C)
{
  __shared__ float tile[32][33];
  const int tx = threadIdx.x & 31, ty = threadIdx.x >> 5;
  const int c0 = blockIdx.x * 32, r0 = blockIdx.y * 32;
#pragma unroll
  for (int i = 0; i < 4; ++i) {
    int r = ty + i * 8;
    tile[r][tx] = in[(size_t)(r0 + r) * C + c0 + tx];
  }
  __syncthreads();
#pragma unroll
  for (int i = 0; i < 4; ++i) {
    int cc = ty + i * 8;
    out[(size_t)(c0 + cc) * R + r0 + tx] = (_Float16)tile[tx][cc];
  }
}

// --- batched fp32 -> fp16 transpose of P (z<32) and H (z>=32): out[z][c][r] ---
__global__ __launch_bounds__(256) void transpose_f16_ph(
    const float* __restrict__ P, const float* __restrict__ Hh,
    _Float16* __restrict__ out)
{
  __shared__ float tile[32][33];
  const int zz = blockIdx.z;
  const float* in = (zz < 32 ? P : Hh) + (size_t)(zz & 31) * (256 * 1024);
  _Float16* o = out + (size_t)zz * (1024 * 256);
  const int tx = threadIdx.x & 31, ty = threadIdx.x >> 5;
  const int c0 = blockIdx.x * 32, r0 = blockIdx.y * 32;   // c over 1024, r over 256
#pragma unroll
  for (int i = 0; i < 4; ++i) {
    int r = ty + i * 8;
    tile[r][tx] = in[(size_t)(r0 + r) * 1024 + c0 + tx];
  }
  __syncthreads();
#pragma unroll
  for (int i = 0; i < 4; ++i) {
    int cc = ty + i * 8;
    o[(size_t)(c0 + cc) * 256 + r0 + tx] = (_Float16)tile[tx][cc];
  }
}

// --- fp16 [256x256] batched transpose (attn -> attnT), bit-copy as short ---
__global__ __launch_bounds__(256) void transpose_b2b(
    const short* __restrict__ in, short* __restrict__ out,
    int R, int C, long sIn, long sOut)
{
  __shared__ short tile[32][33];
  in  += (size_t)blockIdx.z * sIn;
  out += (size_t)blockIdx.z * sOut;
  const int tx = threadIdx.x & 31, ty = threadIdx.x >> 5;
  const int c0 = blockIdx.x * 32, r0 = blockIdx.y * 32;
#pragma unroll
  for (int i = 0; i < 4; ++i) {
    int r = ty + i * 8;
    tile[r][tx] = in[(size_t)(r0 + r) * C + c0 + tx];
  }
  __syncthreads();
#pragma unroll
  for (int i = 0; i < 4; ++i) {
    int cc = ty + i * 8;
    out[(size_t)(c0 + cc) * R + r0 + tx] = tile[tx][cc];
  }
}

// --- input conv: fp32 [P;H] -> split bf16 planes + fp16 Cat left halves ---
__global__ __launch_bounds__(256) void conv_in(
    const float* __restrict__ P, const float* __restrict__ Hh,
    short* __restrict__ oh, short* __restrict__ ol, _Float16* __restrict__ cat)
{
  const int zz = blockIdx.z;                       // 0 = P, 1 = H
  const float* in = zz ? Hh : P;
  oh  += (size_t)zz * 8192 * 1024;
  ol  += (size_t)zz * 8192 * 1024;
  cat += (size_t)zz * 8192 * 2048;
  size_t i = ((size_t)blockIdx.x * 256 + threadIdx.x) * 4;
  float4 v = *(const float4*)&in[i];
  short4 h, l;
  split2(v.x, h.x, l.x); split2(v.y, h.y, l.y);
  split2(v.z, h.z, l.z); split2(v.w, h.w, l.w);
  *(short4*)&oh[i] = h;
  *(short4*)&ol[i] = l;
  size_t row = i >> 10;
  int col    = (int)(i & 1023);
  half4_t c16;
  c16.x = (_Float16)v.x; c16.y = (_Float16)v.y;
  c16.z = (_Float16)v.z; c16.w = (_Float16)v.w;
  *(half4_t*)&cat[row * 2048 + col] = c16;
}

// --- fp32 -> split bf16 (contiguous) ---
__global__ __launch_bounds__(256) void conv_split(
    const float* __restrict__ in, short* __restrict__ oh, short* __restrict__ ol,
    int n)
{
  int i = (blockIdx.x * 256 + threadIdx.x) * 4;
  if (i < n) {
    float4 v = *(const float4*)&in[i];
    short4 h, l;
    split2(v.x, h.x, l.x); split2(v.y, h.y, l.y);
    split2(v.z, h.z, l.z); split2(v.w, h.w, l.w);
    *(short4*)&oh[i] = h;
    *(short4*)&ol[i] = l;
  }
}

__global__ __launch_bounds__(256) void zero_f32(float* __restrict__ p, int n)
{
  int i = blockIdx.x * 256 + threadIdx.x;
  if (i < n) p[i] = 0.0f;
}

// --- softmax over rows of 256 (one wave per row), fp32 -> fp16 ---
__global__ __launch_bounds__(256) void softmax_rows(
    const float* __restrict__ e, _Float16* __restrict__ attn)
{
  const int row  = blockIdx.x * 4 + (threadIdx.x >> 6);
  const int lane = threadIdx.x & 63;
  const float4 v = *(const float4*)&e[(size_t)row * 256 + lane * 4];
  float m = fmaxf(fmaxf(v.x, v.y), fmaxf(v.z, v.w));
#pragma unroll
  for (int off = 32; off; off >>= 1) m = fmaxf(m, __shfl_xor(m, off));
  float e0 = __expf(v.x - m), e1 = __expf(v.y - m);
  float e2 = __expf(v.z - m), e3 = __expf(v.w - m);
  float s = e0 + e1 + e2 + e3;
#pragma unroll
  for (int off = 32; off; off >>= 1) s += __shfl_xor(s, off);
  float inv = 1.0f / s;
  half4_t o;
  o.x = (_Float16)(e0 * inv); o.y = (_Float16)(e1 * inv);
  o.z = (_Float16)(e2 * inv); o.w = (_Float16)(e3 * inv);
  *(half4_t*)&attn[(size_t)row * 256 + lane * 4] = o;
}

// --- a1 = tanh(c + bias) -> split bf16 ---
__global__ __launch_bounds__(256) void bias_tanh_split(
    const float* __restrict__ c, const float* __restrict__ bias,
    short* __restrict__ oh, short* __restrict__ ol, int n)
{
  int i = blockIdx.x * 256 + threadIdx.x;
  if (i < n) {
    float v = fast_tanh(c[i] + bias[i & 2047]);
    short hi, lo; split2(v, hi, lo);
    oh[i] = hi;
    ol[i] = lo;
  }
}

// --- logits: block b: out[b][0..2] = tanh(c2f[b]+b2) @ W3 + b3 ---
__global__ __launch_bounds__(256) void logits2(
    const float* __restrict__ c2f, const float* __restrict__ b2,
    const float* __restrict__ W3, const float* __restrict__ b3,
    float* __restrict__ out)
{
  const int b = blockIdx.x, t = threadIdx.x;
  float p0 = 0.f, p1 = 0.f, p2 = 0.f;
  for (int k = t; k < 2048; k += 256) {
    float a = fast_tanh(c2f[b * 2048 + k] + b2[k]);
    p0 += a * W3[k * 3 + 0];
    p1 += a * W3[k * 3 + 1];
    p2 += a * W3[k * 3 + 2];
  }
#pragma unroll
  for (int off = 32; off; off >>= 1) {
    p0 += __shfl_xor(p0, off);
    p1 += __shfl_xor(p1, off);
    p2 += __shfl_xor(p2, off);
  }
  __shared__ float red[4][3];
  if ((t & 63) == 0) {
    red[t >> 6][0] = p0; red[t >> 6][1] = p1; red[t >> 6][2] = p2;
  }
  __syncthreads();
  if (t < 3) out[b * 3 + t] = b3[t] + red[0][t] + red[1][t] + red[2][t] + red[3][t];
}

extern "C" void kernel_launch(void* const* d_in, const int* in_sizes, int n_in,
                              void* d_out, int out_size, void* d_ws, size_t ws_size,
                              hipStream_t stream) {
  (void)in_sizes; (void)n_in; (void)out_size; (void)ws_size;
  const float* P   = (const float*)d_in[0];
  const float* H   = (const float*)d_in[1];
  const float* W_F = (const float*)d_in[2];
  const float* W_G = (const float*)d_in[3];
  const float* W1  = (const float*)d_in[4];
  const float* b1  = (const float*)d_in[5];
  const float* W2  = (const float*)d_in[6];
  const float* b2  = (const float*)d_in[7];
  const float* W3  = (const float*)d_in[8];
  const float* b3  = (const float*)d_in[9];
  float* out = (float*)d_out;

  char* wsp = (char*)d_ws;
  auto alloc = [&](size_t bytes) {
    char* p = wsp;
    wsp += (bytes + 255) & ~(size_t)255;
    return p;
  };
  short*    Pp_h  = (short*)alloc(16384ull * 1024 * 2);     // [P;H] split planes
  short*    Pp_l  = (short*)alloc(16384ull * 1024 * 2);
  _Float16* Cat16 = (_Float16*)alloc(16384ull * 2048 * 2);  // [P|betas ; H|alphas]
  short*    Fbuf  = (short*)alloc(32ull * 1024 * 1024 * 2); // 64 MB multi-use
  short*    WFT_h = (short*)alloc(1024ull * 1024 * 2);
  short*    WFT_l = (short*)alloc(1024ull * 1024 * 2);
  _Float16* WGT16 = (_Float16*)alloc(2048ull * 2048 * 2);
  float*    eijs  = (float*)alloc(32ull * 256 * 256 * 4);
  _Float16* attn  = (_Float16*)alloc(32ull * 256 * 256 * 2);
  _Float16* attnT = (_Float16*)alloc(32ull * 256 * 256 * 2);
  float*    agg   = (float*)alloc(32ull * 4096 * 4);
  short*    aggb_h= (short*)alloc(128ull * 4096 * 2);       // 128-row pad (M=32)
  short*    aggb_l= (short*)alloc(128ull * 4096 * 2);
  float*    c1f   = (float*)alloc(32ull * 2048 * 4);
  float*    c2f   = (float*)alloc(32ull * 2048 * 4);
  short*    a1_h  = (short*)alloc(128ull * 2048 * 2);
  short*    a1_l  = (short*)alloc(128ull * 2048 * 2);

  // Fbuf phase 1: F split planes (2 x 32 MB)
  short* F_h = Fbuf;
  short* F_l = Fbuf + 16384ull * 1024;
  // Fbuf phase 2: PHbT fp16 (64 batches x [1024][256] = 32 MB); z<32=P^T, z>=32=H^T
  _Float16* PHbT = (_Float16*)Fbuf;
  _Float16* PbT  = PHbT;
  _Float16* HbT  = PHbT + 32ull * 1024 * 256;
  // Fbuf phase 3: W1^T (2 x 16 MB) + W2^T (2 x 8 MB) split planes
  short* W1T_h = Fbuf;
  short* W1T_l = Fbuf +  8ull * 1024 * 1024;
  short* W2T_h = Fbuf + 16ull * 1024 * 1024;
  short* W2T_l = Fbuf + 20ull * 1024 * 1024;

  // 1. input conversions (P+H fused), weight transposes
  conv_in<<<dim3(8192, 1, 2), 256, 0, stream>>>(P, H, Pp_h, Pp_l, Cat16);
  transpose_split<<<dim3(32, 32, 1), 256, 0, stream>>>(W_F, WFT_h, WFT_l, 1024, 1024);
  transpose_f16<<<dim3(64, 64, 1), 256, 0, stream>>>(W_G, WGT16, 2048, 2048);

  // 2. F = tanh([P;H] @ W_F), split bf16x3, split store
  gemm_nt_split<1, 1><<<dim3(128, 8, 1), 256, 0, stream>>>(
      Pp_h, Pp_l, 1024, 0, WFT_h, WFT_l, 1024, 0,
      F_h, F_l, 1024, 0, 16384, 1024, 1);

  // 3. scores E[z] = F_p[z] @ F_h[z]^T, split bf16x3, split-K x4 (atomic fp32)
  zero_f32<<<8192, 256, 0, stream>>>(eijs, 32 * 256 * 256);
  gemm_nt_split<0, 0><<<dim3(2, 2, 128), 256, 0, stream>>>(
      F_h, F_l, 1024, 256 * 1024,
      F_h + 8192ull * 1024, F_l + 8192ull * 1024, 1024, 256 * 1024,
      eijs, nullptr, 256, 65536, 256, 1024, 4);

  // 4. softmax -> fp16 attn; attn^T; P^T/H^T fp16 (fused) into Fbuf
  softmax_rows<<<2048, 256, 0, stream>>>(eijs, attn);
  transpose_b2b<<<dim3(8, 8, 32), 256, 0, stream>>>(
      (const short*)attn, (short*)attnT, 256, 256, 65536, 65536);
  transpose_f16_ph<<<dim3(32, 8, 64), 256, 0, stream>>>(P, H, PHbT);

  // 5. betas = attn @ H -> Cat1 right; alphas = attn^T @ P -> Cat2 right (fp16)
  gemm_f16<1><<<dim3(2, 8, 32), 256, 0, stream>>>(
      attn, 256, 65536, HbT, 256, 1024 * 256,
      Cat16 + 1024, 2048, 256 * 2048, 256, nullptr);
  gemm_f16<1><<<dim3(2, 8, 32), 256, 0, stream>>>(
      attnT, 256, 65536, PbT, 256, 1024 * 256,
      Cat16 + 8192ull * 2048 + 1024, 2048, 256 * 2048, 256, nullptr);

  // 6. V = tanh(Cat @ W_G) fused column-sum -> agg (fp16, BK=64)
  zero_f32<<<512, 256, 0, stream>>>(agg, 32 * 4096);
  gemm_f16<2><<<dim3(128, 16, 1), 256, 0, stream>>>(
      Cat16, 2048, 0, WGT16, 2048, 0, nullptr, 0, 0, 2048, agg);

  // 7. classifier: split-K split-bf16 GEMMs + epilogues
  transpose_split<<<dim3(64, 128, 1), 256, 0, stream>>>(W1, W1T_h, W1T_l, 4096, 2048);
  transpose_split<<<dim3(64, 64, 1),  256, 0, stream>>>(W2, W2T_h, W2T_l, 2048, 2048);
  conv_split<<<128, 256, 0, stream>>>(agg, aggb_h, aggb_l, 32 * 4096);
  zero_f32<<<256, 256, 0, stream>>>(c1f, 32 * 2048);
  gemm_nt_split<0, 0><<<dim3(1, 16, 8), 256, 0, stream>>>(
      aggb_h, aggb_l, 4096, 0, W1T_h, W1T_l, 4096, 0,
      c1f, nullptr, 2048, 0, 32, 4096, 8);
  bias_tanh_split<<<256, 256, 0, stream>>>(c1f, b1, a1_h, a1_l, 32 * 2048);
  zero_f32<<<256, 256, 0, stream>>>(c2f, 32 * 2048);
  gemm_nt_split<0, 0><<<dim3(1, 16, 4), 256, 0, stream>>>(
      a1_h, a1_l, 2048, 0, W2T_h, W2T_l, 2048, 0,
      c2f, nullptr, 2048, 0, 32, 2048, 4);
  logits2<<<32, 256, 0, stream>>>(c2f, b2, W3, b3, out);
}